// Round 2
// baseline (864.182 us; speedup 1.0000x reference)
//
#include <hip/hip_runtime.h>

// ---------------------------------------------------------------------------
// TransformerBlock on MI355X (gfx950).
// Pipeline:
//   T1: transpose+cast weights Wk,Wq,Wo,W1,W2 -> bf16 B^T form; value -> VT
//   T2: cast key,query -> bf16
//   G1: kp = keyB @ WkT          [16384,512]   bf16 out
//   G2: qp = qryB @ WqT          [16384,512]   bf16 out
//   G3: E  = qp @ kp^T  (x16)    [16,1024,1024] f32 out
//   S : P  = softmax(E/sqrt512)  bf16 out
//   G4: O  = P @ value  (x16)    [16,1024,512] bf16 out
//   G5: out2 = O @ WoT + bo      f32 out
//   L1: LN(concat(out2,q)) -> LN(concat(.,q)) -> xln bf16 [16384,1536]
//   G6: h = relu(xln @ W1T + bf1) bf16 [16384,3072]
//   G7: f = h @ W2T + bf2        f32 [16384,1536]
//   L2: out = LN(f)              f32 -> d_out
// GEMM = m97 structure: 128x128 tile, BK=32, 4 waves, global_load_lds(16B),
// 16x16x32 bf16 MFMA, 4x4 fragments/wave.
// Workspace peak 210.8 MB (buffer lifetimes verified stage-by-stage below).
// ---------------------------------------------------------------------------

typedef __attribute__((ext_vector_type(8))) __bf16 bf16x8;
typedef __attribute__((ext_vector_type(4))) float f32x4;

#define DEV static __device__ __forceinline__

DEV unsigned short f2bf(float f) {
  union { float f; unsigned int u; } x; x.f = f;
  unsigned int u = x.u + 0x7fffu + ((x.u >> 16) & 1u);   // RNE
  return (unsigned short)(u >> 16);
}

DEV void gll16(const void* g, void* l) {
  __builtin_amdgcn_global_load_lds(
      (const __attribute__((address_space(1))) void*)g,
      (__attribute__((address_space(3))) void*)l, 16, 0, 0);
}

// ---------------- GEMM: C[M,N] = A[M,K](bf16) * Bt[N,K](bf16)^T -------------
// 128x128 tile, BK=32, 4 waves (2x2), each wave 64x64 out (4x4 fragments).
template <typename CT, bool BIAS, bool RELU>
__global__ __launch_bounds__(256)
void gemm_bt(const unsigned short* __restrict__ A,
             const unsigned short* __restrict__ Bt,
             CT* __restrict__ C, const float* __restrict__ bias,
             int M, int N, int K,
             long long sA, long long sB, long long sC) {
  __shared__ __align__(16) unsigned short ldsA[128 * 32];
  __shared__ __align__(16) unsigned short ldsB[128 * 32];
  const int t = threadIdx.x;
  const int w = t >> 6, lane = t & 63;
  A  += (long long)blockIdx.z * sA;
  Bt += (long long)blockIdx.z * sB;
  C  += (long long)blockIdx.z * sC;
  const int rowBase = blockIdx.y * 128;
  const int colBase = blockIdx.x * 128;
  const int wm = w >> 1, wn = w & 1;

  // staging: 512 chunks of 16B per tile; chunk c -> row c>>2, cols (c&3)*8..+8
  // LDS byte offset of chunk c = (c>>2)*64 + (c&3)*16 = c*16  (lane-linear,
  // matches global_load_lds wave-uniform-base + lane*16 write rule)
  const int c0 = t, c1 = t + 256;
  const int ra0 = c0 >> 2, ca0 = (c0 & 3) << 3;
  const int ra1 = c1 >> 2, ca1 = (c1 & 3) << 3;
  const unsigned short* gA0 = A + (long long)(rowBase + ra0) * K + ca0;
  const unsigned short* gA1 = A + (long long)(rowBase + ra1) * K + ca1;
  const unsigned short* gB0 = Bt + (long long)(colBase + ra0) * K + ca0;
  const unsigned short* gB1 = Bt + (long long)(colBase + ra1) * K + ca1;
  char* dA0 = (char*)ldsA + w * 1024;
  char* dA1 = (char*)ldsA + 4096 + w * 1024;
  char* dB0 = (char*)ldsB + w * 1024;
  char* dB1 = (char*)ldsB + 4096 + w * 1024;

  f32x4 acc[4][4];
#pragma unroll
  for (int m = 0; m < 4; ++m)
#pragma unroll
    for (int n = 0; n < 4; ++n) acc[m][n] = f32x4{0.f, 0.f, 0.f, 0.f};

  // A-frag: row = lane&15, k = (lane>>4)*8 + j   (m89/m91 verified)
  const unsigned short* pa = &ldsA[(wm * 64 + (lane & 15)) * 32 + ((lane >> 4) << 3)];
  const unsigned short* pb = &ldsB[(wn * 64 + (lane & 15)) * 32 + ((lane >> 4) << 3)];

  for (int k0 = 0; k0 < K; k0 += 32) {
    gll16(gA0 + k0, dA0);
    gll16(gA1 + k0, dA1);
    gll16(gB0 + k0, dB0);
    gll16(gB1 + k0, dB1);
    __syncthreads();   // compiler drains vmcnt before s_barrier (m97 behavior)
    bf16x8 av[4], bv[4];
#pragma unroll
    for (int m = 0; m < 4; ++m) av[m] = *(const bf16x8*)(pa + m * 512);
#pragma unroll
    for (int n = 0; n < 4; ++n) bv[n] = *(const bf16x8*)(pb + n * 512);
#pragma unroll
    for (int m = 0; m < 4; ++m)
#pragma unroll
      for (int n = 0; n < 4; ++n)
        acc[m][n] = __builtin_amdgcn_mfma_f32_16x16x32_bf16(av[m], bv[n], acc[m][n], 0, 0, 0);
    __syncthreads();
  }

  // C/D: col = lane&15, row = (lane>>4)*4 + r   (m89/m91 verified)
  const int r0 = rowBase + wm * 64 + ((lane >> 4) << 2);
  const int cbase = colBase + wn * 64 + (lane & 15);
#pragma unroll
  for (int n = 0; n < 4; ++n) {
    const int col = cbase + n * 16;
    float bvv = 0.f;
    if constexpr (BIAS) bvv = bias[col];
#pragma unroll
    for (int m = 0; m < 4; ++m) {
#pragma unroll
      for (int r = 0; r < 4; ++r) {
        float v = acc[m][n][r] + bvv;
        if constexpr (RELU) v = v > 0.f ? v : 0.f;
        const long long idx = (long long)(r0 + m * 16 + r) * N + col;
        if constexpr (sizeof(CT) == 2) C[idx] = (CT)f2bf(v);
        else                           C[idx] = (CT)v;
      }
    }
  }
}

// ---------------- transpose + cast f32 -> bf16: dst[c][r] = src[r][c] -------
__global__ void transpose_cast_k(const float* __restrict__ src,
                                 unsigned short* __restrict__ dst,
                                 int R, int Ccols, long long sS, long long sD) {
  __shared__ float tile[32][33];
  src += (long long)blockIdx.z * sS;
  dst += (long long)blockIdx.z * sD;
  const int rb = blockIdx.y * 32, cb = blockIdx.x * 32;
  const int tx = threadIdx.x, ty = threadIdx.y;  // 32 x 8
#pragma unroll
  for (int k = 0; k < 4; ++k)
    tile[ty + k * 8][tx] = src[(long long)(rb + ty + k * 8) * Ccols + cb + tx];
  __syncthreads();
#pragma unroll
  for (int k = 0; k < 4; ++k)
    dst[(long long)(cb + ty + k * 8) * R + rb + tx] = f2bf(tile[tx][ty + k * 8]);
}

// ---------------- plain cast f32 -> bf16 ------------------------------------
__global__ void cast_f32_bf16_k(const float* __restrict__ src,
                                unsigned short* __restrict__ dst, long long n4) {
  long long i = (long long)blockIdx.x * 256 + threadIdx.x;
  const long long stride = (long long)gridDim.x * 256;
  for (; i < n4; i += stride) {
    float4 v = ((const float4*)src)[i];
    ushort4 o;
    o.x = f2bf(v.x); o.y = f2bf(v.y); o.z = f2bf(v.z); o.w = f2bf(v.w);
    ((ushort4*)dst)[i] = o;
  }
}

// ---------------- row softmax over 1024, f32 in, bf16 out -------------------
__global__ __launch_bounds__(256)
void softmax_k(const float* __restrict__ E, unsigned short* __restrict__ P) {
  __shared__ float sm[8];
  const long long row = blockIdx.x;
  const int t = threadIdx.x, w = t >> 6, lane = t & 63;
  float4 v = ((const float4*)E)[row * 256 + t];
  const float scale = 0.044194173824159216f;  // 1/sqrt(512)
  v.x *= scale; v.y *= scale; v.z *= scale; v.w *= scale;
  float mx = fmaxf(fmaxf(v.x, v.y), fmaxf(v.z, v.w));
#pragma unroll
  for (int m = 1; m < 64; m <<= 1) mx = fmaxf(mx, __shfl_xor(mx, m));
  if (lane == 0) sm[w] = mx;
  __syncthreads();
  mx = fmaxf(fmaxf(sm[0], sm[1]), fmaxf(sm[2], sm[3]));
  float e0 = __expf(v.x - mx), e1 = __expf(v.y - mx);
  float e2 = __expf(v.z - mx), e3 = __expf(v.w - mx);
  float s = e0 + e1 + e2 + e3;
#pragma unroll
  for (int m = 1; m < 64; m <<= 1) s += __shfl_xor(s, m);
  if (lane == 0) sm[4 + w] = s;
  __syncthreads();
  s = sm[4] + sm[5] + sm[6] + sm[7];
  const float inv = 1.0f / s;
  ushort4 o;
  o.x = f2bf(e0 * inv); o.y = f2bf(e1 * inv);
  o.z = f2bf(e2 * inv); o.w = f2bf(e3 * inv);
  ((ushort4*)P)[row * 256 + t] = o;
}

// ---------------- block reduce (sum pair) -----------------------------------
DEV void breduce2(float& a, float& b, float* sm, int w, int lane) {
#pragma unroll
  for (int m = 1; m < 64; m <<= 1) { a += __shfl_xor(a, m); b += __shfl_xor(b, m); }
  if (lane == 0) { sm[w] = a; sm[4 + w] = b; }
  __syncthreads();
  a = sm[0] + sm[1] + sm[2] + sm[3];
  b = sm[4] + sm[5] + sm[6] + sm[7];
  __syncthreads();
}

// ---- LN(concat(out2,q)) then LN(concat(attn_out,q)) -> xln bf16 [row,1536] -
__global__ __launch_bounds__(256)
void ln_concat_k(const float* __restrict__ out2, const float* __restrict__ query,
                 const float* __restrict__ ga, const float* __restrict__ ba,
                 const float* __restrict__ g1, const float* __restrict__ b1,
                 unsigned short* __restrict__ xln) {
  __shared__ float sm[8];
  const long long row = blockIdx.x;
  const int t = threadIdx.x, w = t >> 6, lane = t & 63;
  const float* o = out2 + row * 512;
  const float* q = query + row * 512;
  float c0 = o[t], c1 = o[t + 256], c2 = q[t], c3 = q[t + 256];
  float s = c0 + c1 + c2 + c3;
  float ss = c0 * c0 + c1 * c1 + c2 * c2 + c3 * c3;
  breduce2(s, ss, sm, w, lane);
  float mu = s * (1.0f / 1024.0f);
  float var = ss * (1.0f / 1024.0f) - mu * mu;
  float rs = rsqrtf(var + 1e-5f);
  float a0 = (c0 - mu) * rs * ga[t] + ba[t];
  float a1 = (c1 - mu) * rs * ga[t + 256] + ba[t + 256];
  float a2 = (c2 - mu) * rs * ga[t + 512] + ba[t + 512];
  float a3 = (c3 - mu) * rs * ga[t + 768] + ba[t + 768];
  float s2 = a0 + a1 + a2 + a3 + c2 + c3;
  float ss2 = a0*a0 + a1*a1 + a2*a2 + a3*a3 + c2*c2 + c3*c3;
  breduce2(s2, ss2, sm, w, lane);
  float mu2 = s2 * (1.0f / 1536.0f);
  float var2 = ss2 * (1.0f / 1536.0f) - mu2 * mu2;
  float rs2 = rsqrtf(var2 + 1e-5f);
  unsigned short* xr = xln + row * 1536;
  xr[t]        = f2bf((a0 - mu2) * rs2 * g1[t] + b1[t]);
  xr[t + 256]  = f2bf((a1 - mu2) * rs2 * g1[t + 256] + b1[t + 256]);
  xr[t + 512]  = f2bf((a2 - mu2) * rs2 * g1[t + 512] + b1[t + 512]);
  xr[t + 768]  = f2bf((a3 - mu2) * rs2 * g1[t + 768] + b1[t + 768]);
  xr[t + 1024] = f2bf((c2 - mu2) * rs2 * g1[t + 1024] + b1[t + 1024]);
  xr[t + 1280] = f2bf((c3 - mu2) * rs2 * g1[t + 1280] + b1[t + 1280]);
}

// ---------------- final LN over 1536, f32 -> f32 ----------------------------
__global__ __launch_bounds__(256)
void ln_final_k(const float* __restrict__ f, const float* __restrict__ g2,
                const float* __restrict__ b2, float* __restrict__ out) {
  __shared__ float sm[8];
  const long long row = blockIdx.x;
  const int t = threadIdx.x, w = t >> 6, lane = t & 63;
  const float* fr = f + row * 1536;
  float v[6];
  float s = 0.f, ss = 0.f;
#pragma unroll
  for (int j = 0; j < 6; ++j) { v[j] = fr[t + j * 256]; s += v[j]; ss += v[j] * v[j]; }
  breduce2(s, ss, sm, w, lane);
  float mu = s * (1.0f / 1536.0f);
  float var = ss * (1.0f / 1536.0f) - mu * mu;
  float rs = rsqrtf(var + 1e-5f);
  float* orow = out + row * 1536;
#pragma unroll
  for (int j = 0; j < 6; ++j)
    orow[t + j * 256] = (v[j] - mu) * rs * g2[t + j * 256] + b2[t + j * 256];
}

// ---------------------------------------------------------------------------
extern "C" void kernel_launch(void* const* d_in, const int* in_sizes, int n_in,
                              void* d_out, int out_size, void* d_ws, size_t ws_size,
                              hipStream_t stream) {
  const float* value = (const float*)d_in[0];
  const float* key   = (const float*)d_in[1];
  const float* query = (const float*)d_in[2];
  const float* Wk  = (const float*)d_in[3];
  const float* Wq  = (const float*)d_in[4];
  const float* Wo  = (const float*)d_in[5];
  const float* bo  = (const float*)d_in[6];
  const float* ga  = (const float*)d_in[7];
  const float* ba  = (const float*)d_in[8];
  const float* g1  = (const float*)d_in[9];
  const float* b1  = (const float*)d_in[10];
  const float* W1  = (const float*)d_in[11];
  const float* bf1 = (const float*)d_in[12];
  const float* W2  = (const float*)d_in[13];
  const float* bf2 = (const float*)d_in[14];
  const float* g2  = (const float*)d_in[15];
  const float* b2  = (const float*)d_in[16];
  float* out = (float*)d_out;
  char* ws = (char*)d_ws;

  // ---- workspace map (bytes), peak 210,763,776 B ≈ 201 MB -----------------
  // Lifetime-checked reuse:
  //   E  lives in the future-h zone (dead before G6 writes h)
  //   P  reuses keyB+qryB (dead after G1/G2)
  //   O  reuses kp (dead after G3)
  //   out2 reuses qp + start of E zone (both dead by G5)
  //   xln reuses P+O zones (dead after G4/G5)
  //   f  reuses [0,96M): W1T/WkT/WqT/WoT/VT/xln all dead at G7
  const size_t oW1T = 0;                   // [3072][1536] bf16, 9,437,184
  const size_t oWkT = 9437184;             // 512x512 bf16
  const size_t oWqT = 9961472;
  const size_t oWoT = 10485760;
  const size_t oVT  = 11010048;            // [16][512][1024] bf16, 16 MB
  const size_t oKeyB = 27787264;           // [16384][512] bf16, 16 MB
  const size_t oQryB = 44564480;           // 16 MB
  const size_t oKp   = 61341696;           // 16 MB
  const size_t oQp   = 78118912;           // 16 MB
  const size_t oE    = 100663296;          // [16][1024][1024] f32, 64 MB
  const size_t oP    = oKeyB;              // [16,1024,1024] bf16, 32 MB (keyB+qryB)
  const size_t oO    = oKp;                // [16384][512] bf16, 16 MB
  const size_t oOut2 = oQp;                // [16384][512] f32, 32 MB (qp + E-head)
  const size_t oXln  = 27787264;           // [16384][1536] bf16, 48 MB (P+O zones)
  const size_t oH    = 100663296;          // [16384][3072] bf16, 96 MB (E zone +)
  const size_t oW2T  = 201326592;          // [1536][3072] bf16, 9,437,184
  const size_t oF    = 0;                  // [16384][1536] f32, 96 MB

  unsigned short* W1T = (unsigned short*)(ws + oW1T);
  unsigned short* WkT = (unsigned short*)(ws + oWkT);
  unsigned short* WqT = (unsigned short*)(ws + oWqT);
  unsigned short* WoT = (unsigned short*)(ws + oWoT);
  unsigned short* W2T = (unsigned short*)(ws + oW2T);
  unsigned short* VT  = (unsigned short*)(ws + oVT);
  unsigned short* keyB = (unsigned short*)(ws + oKeyB);
  unsigned short* qryB = (unsigned short*)(ws + oQryB);
  unsigned short* kp  = (unsigned short*)(ws + oKp);
  unsigned short* qp  = (unsigned short*)(ws + oQp);
  float*          E   = (float*)(ws + oE);
  unsigned short* P   = (unsigned short*)(ws + oP);
  unsigned short* O   = (unsigned short*)(ws + oO);
  float*          out2 = (float*)(ws + oOut2);
  unsigned short* xln = (unsigned short*)(ws + oXln);
  unsigned short* h   = (unsigned short*)(ws + oH);
  float*          f   = (float*)(ws + oF);

  const dim3 tb(32, 8);
  // weight transposes (B^T form) + value transpose
  transpose_cast_k<<<dim3(16, 16, 1), tb, 0, stream>>>(Wk, WkT, 512, 512, 0, 0);
  transpose_cast_k<<<dim3(16, 16, 1), tb, 0, stream>>>(Wq, WqT, 512, 512, 0, 0);
  transpose_cast_k<<<dim3(16, 16, 1), tb, 0, stream>>>(Wo, WoT, 512, 512, 0, 0);
  transpose_cast_k<<<dim3(96, 48, 1), tb, 0, stream>>>(W1, W1T, 1536, 3072, 0, 0);
  transpose_cast_k<<<dim3(48, 96, 1), tb, 0, stream>>>(W2, W2T, 3072, 1536, 0, 0);
  transpose_cast_k<<<dim3(16, 32, 16), tb, 0, stream>>>(value, VT, 1024, 512, 524288, 524288);
  // input casts
  cast_f32_bf16_k<<<2048, 256, 0, stream>>>(key,   keyB, 2097152);
  cast_f32_bf16_k<<<2048, 256, 0, stream>>>(query, qryB, 2097152);
  // projections
  gemm_bt<unsigned short, false, false><<<dim3(4, 128, 1), 256, 0, stream>>>(
      keyB, WkT, kp, nullptr, 16384, 512, 512, 0, 0, 0);
  gemm_bt<unsigned short, false, false><<<dim3(4, 128, 1), 256, 0, stream>>>(
      qryB, WqT, qp, nullptr, 16384, 512, 512, 0, 0, 0);
  // energy (batched): E[b] = qp[b] @ kp[b]^T
  gemm_bt<float, false, false><<<dim3(8, 8, 16), 256, 0, stream>>>(
      qp, kp, E, nullptr, 1024, 1024, 512, 524288, 524288, 1048576);
  // softmax rows
  softmax_k<<<16384, 256, 0, stream>>>(E, P);
  // PV (batched): O[b] = P[b] @ value[b]
  gemm_bt<unsigned short, false, false><<<dim3(4, 8, 16), 256, 0, stream>>>(
      P, VT, O, nullptr, 1024, 512, 1024, 1048576, 524288, 524288);
  // out2 = O @ Wo + bo
  gemm_bt<float, true, false><<<dim3(4, 128, 1), 256, 0, stream>>>(
      O, WoT, out2, bo, 16384, 512, 512, 0, 0, 0);
  // LN(concat) x2 -> xln
  ln_concat_k<<<16384, 256, 0, stream>>>(out2, query, ga, ba, g1, b1, xln);
  // h = relu(xln @ W1 + bf1)
  gemm_bt<unsigned short, true, true><<<dim3(24, 128, 1), 256, 0, stream>>>(
      xln, W1T, h, bf1, 16384, 3072, 1536, 0, 0, 0);
  // f = h @ W2 + bf2
  gemm_bt<float, true, false><<<dim3(12, 128, 1), 256, 0, stream>>>(
      h, W2T, f, bf2, 16384, 1536, 3072, 0, 0, 0);
  // final LN -> d_out
  ln_final_k<<<16384, 256, 0, stream>>>(f, g2, b2, out);
}

// Round 9
// 771.192 us; speedup vs baseline: 1.1206x; 1.1206x over previous
//
#include <hip/hip_runtime.h>

// ---------------------------------------------------------------------------
// TransformerBlock on MI355X (gfx950).
// GEMM: 256x256 tile, BK=32, 4-slot LDS ring (128 KiB), 8 waves (2Mx4N),
// stage-3-tiles-ahead with counted vmcnt(8) (T3+T4), LDS XOR swizzle via
// pre-swizzled global source (T2, m173 pattern), setprio around MFMA (T5),
// XCD-bijective block swizzle (T1). 16x16x32 bf16 MFMA, acc 8x4 frags/wave.
// Pipeline (unchanged): T1 transposes/casts -> G1 kp -> G2 qp -> G3 E ->
// softmax -> G4 PV -> G5 out2 -> LN-fuse -> G6 W1+ReLU -> G7 W2 -> LN final.
// Desk-checked r4: ring WAR/RAW ledger, vmcnt counting, swizzle involution,
// bank histogram (8/bank = minimum), barrier uniformity.
// ---------------------------------------------------------------------------

typedef __attribute__((ext_vector_type(8))) __bf16 bf16x8;
typedef __attribute__((ext_vector_type(4))) float f32x4;

#define DEV static __device__ __forceinline__

DEV unsigned short f2bf(float f) {
  union { float f; unsigned int u; } x; x.f = f;
  unsigned int u = x.u + 0x7fffu + ((x.u >> 16) & 1u);   // RNE
  return (unsigned short)(u >> 16);
}

DEV void gll16(const void* g, void* l) {
  __builtin_amdgcn_global_load_lds(
      (const __attribute__((address_space(1))) void*)g,
      (__attribute__((address_space(3))) void*)l, 16, 0, 0);
}

#define MFMA16(a, b, c) (c) = __builtin_amdgcn_mfma_f32_16x16x32_bf16((a), (b), (c), 0, 0, 0)

// ---------------- GEMM: C[M,N] = A[M,K](bf16) * Bt[N,K](bf16)^T -------------
// 256x256 tile, BK=32. 512 thr = 8 waves: wm=w>>2 (2), wn=w&3 (4).
// Per wave out 128x64 = acc[8][4] f32x4. LDS ring: 4 slots x (A 16KB + B 16KB).
// K-tile t lives in slot t&3; iteration t stages tile t+3 (A in phase1,
// B in phase2) into slot (t+3)&3 == (t-1)&3, whose last reader was iter t-1.
// vmcnt(8) at end of iter t guarantees tile t+1 resident (8 newest loads
// outstanding = tiles t+2,t+3; per-wave wait + s_barrier -> all waves).
// Tail: vmcnt(4) at t=NT-3, vmcnt(0) at t=NT-2.
// LDS swizzle: 16B-granule slot s at row r holds source granule s^((r>>1)&3);
// realized by per-lane swizzled GLOBAL source col (global_load_lds writes
// lane-linear), and the matching XOR on the ds_read address.
template <typename CT, bool BIAS, bool RELU>
__global__ __launch_bounds__(512, 2)
void gemm256(const unsigned short* __restrict__ A,
             const unsigned short* __restrict__ Bt,
             CT* __restrict__ C, const float* __restrict__ bias,
             int M, int N, int K, int nbx, int nby,
             long long sA, long long sB, long long sC) {
  __shared__ __align__(16) unsigned short lds[65536];   // 128 KiB

  // T1: XCD-bijective swizzle (gridDim.x % 8 == 0 at every call site)
  const int cpx = gridDim.x >> 3;
  const int id = blockIdx.x;
  const int swz = (id & 7) * cpx + (id >> 3);
  const int nxy = nbx * nby;
  const int bz = swz / nxy;
  const int rxy = swz - bz * nxy;
  const int by = rxy / nbx;
  const int bx = rxy - by * nbx;

  A  += (long long)bz * sA;
  Bt += (long long)bz * sB;
  C  += (long long)bz * sC;
  const int rowBase = by * 256, colBase = bx * 256;

  const int tid = threadIdx.x;
  const int w = tid >> 6, lane = tid & 63;
  const int wm = w >> 2, wn = w & 3;

  // staging: wave w stages chunks w and w+8 of each 16KB unit.
  // chunk c = rows c*16..c*16+15 (64 B/row); lane l -> row c*16 + (l>>2),
  // 16B slot l&3; source k-granule = (l&3) ^ ((l>>3)&3)  [= (l&3)^((row>>1)&3)]
  const int lr = lane >> 2;
  const int sc = (((lane & 3) ^ ((lane >> 3) & 3)) << 3);   // element offset
  const long long Kll = K;
  const unsigned short* gA0 = A  + (long long)(rowBase + w * 16 + lr) * Kll + sc;
  const unsigned short* gA1 = gA0 + 128 * Kll;              // chunk w+8
  const unsigned short* gB0 = Bt + (long long)(colBase + w * 16 + lr) * Kll + sc;
  const unsigned short* gB1 = gB0 + 128 * Kll;
  char* const Lb = (char*)lds;
  const int dA0 = w * 1024, dA1 = (w + 8) * 1024;           // chunk byte offsets

  // compute-read: row = base + (lane&15); k-granule g = lane>>4 stored at
  // slot g ^ ((row>>1)&3) = g ^ ((lane>>1)&3)   (bases are %16==0)
  const int sig = (lane >> 4) ^ ((lane >> 1) & 3);
  const int aoff = (wm * 128 + (lane & 15)) * 32 + sig * 8;  // ushort offset
  const int boff = (wn * 64 + (lane & 15)) * 32 + sig * 8;

  f32x4 acc[8][4];
#pragma unroll
  for (int m = 0; m < 8; ++m)
#pragma unroll
    for (int n = 0; n < 4; ++n) acc[m][n] = f32x4{0.f, 0.f, 0.f, 0.f};

  const int NT = K >> 5;
  // prologue: stage tiles 0..2
  const int npro = NT < 3 ? NT : 3;
  for (int p = 0; p < npro; ++p) {
    gll16(gA0 + (long long)p * 32, Lb + (p << 15) + dA0);
    gll16(gA1 + (long long)p * 32, Lb + (p << 15) + dA1);
    gll16(gB0 + (long long)p * 32, Lb + (p << 15) + 16384 + dA0);
    gll16(gB1 + (long long)p * 32, Lb + (p << 15) + 16384 + dA1);
  }
  if (NT >= 3) asm volatile("s_waitcnt vmcnt(8)" ::: "memory");  // tile 0 resident
  else         asm volatile("s_waitcnt vmcnt(0)" ::: "memory");
  __builtin_amdgcn_sched_barrier(0);
  __builtin_amdgcn_s_barrier();
  __builtin_amdgcn_sched_barrier(0);

  for (int t = 0; t < NT; ++t) {
    const int slot = t & 3;
    const unsigned short* sa = lds + slot * 16384;
    const unsigned short* sb = sa + 8192;
    // -------- phase 1: read A-frags + B n0/n1; stage A(t+3) --------
    bf16x8 av[8];
#pragma unroll
    for (int m = 0; m < 8; ++m)
      av[m] = *(const bf16x8*)(sa + aoff + m * 512);
    bf16x8 bv0 = *(const bf16x8*)(sb + boff);
    bf16x8 bv1 = *(const bf16x8*)(sb + boff + 512);
    if (t + 3 < NT) {
      const int ss = (t + 3) & 3;
      gll16(gA0 + (long long)(t + 3) * 32, Lb + (ss << 15) + dA0);
      gll16(gA1 + (long long)(t + 3) * 32, Lb + (ss << 15) + dA1);
    }
    __builtin_amdgcn_sched_barrier(0);
    __builtin_amdgcn_s_barrier();
    __builtin_amdgcn_sched_barrier(0);
    __builtin_amdgcn_s_setprio(1);
#pragma unroll
    for (int m = 0; m < 8; ++m) {
      MFMA16(av[m], bv0, acc[m][0]);
      MFMA16(av[m], bv1, acc[m][1]);
    }
    __builtin_amdgcn_s_setprio(0);
    __builtin_amdgcn_sched_barrier(0);
    __builtin_amdgcn_s_barrier();
    // -------- phase 2: read B n2/n3; stage B(t+3); counted vmcnt --------
    bf16x8 bv2 = *(const bf16x8*)(sb + boff + 1024);
    bf16x8 bv3 = *(const bf16x8*)(sb + boff + 1536);
    if (t + 3 < NT) {
      const int ss = (t + 3) & 3;
      gll16(gB0 + (long long)(t + 3) * 32, Lb + (ss << 15) + 16384 + dA0);
      gll16(gB1 + (long long)(t + 3) * 32, Lb + (ss << 15) + 16384 + dA1);
    }
    if (t + 3 < NT)      asm volatile("s_waitcnt vmcnt(8)" ::: "memory");
    else if (t + 2 < NT) asm volatile("s_waitcnt vmcnt(4)" ::: "memory");
    else if (t + 1 < NT) asm volatile("s_waitcnt vmcnt(0)" ::: "memory");
    __builtin_amdgcn_sched_barrier(0);
    __builtin_amdgcn_s_barrier();
    __builtin_amdgcn_sched_barrier(0);
    __builtin_amdgcn_s_setprio(1);
#pragma unroll
    for (int m = 0; m < 8; ++m) {
      MFMA16(av[m], bv2, acc[m][2]);
      MFMA16(av[m], bv3, acc[m][3]);
    }
    __builtin_amdgcn_s_setprio(0);
    __builtin_amdgcn_sched_barrier(0);
    __builtin_amdgcn_s_barrier();
  }

  // -------- epilogue: C/D col = lane&15, row = (lane>>4)*4 + r --------
  const int r0 = rowBase + wm * 128 + ((lane >> 4) << 2);
  const int cb = colBase + wn * 64 + (lane & 15);
#pragma unroll
  for (int n = 0; n < 4; ++n) {
    const int col = cb + n * 16;
    float bvv = 0.f;
    if constexpr (BIAS) bvv = bias[col];
#pragma unroll
    for (int m = 0; m < 8; ++m) {
#pragma unroll
      for (int r = 0; r < 4; ++r) {
        float v = acc[m][n][r] + bvv;
        if constexpr (RELU) v = v > 0.f ? v : 0.f;
        const long long idx = (long long)(r0 + m * 16 + r) * N + col;
        if constexpr (sizeof(CT) == 2) C[idx] = (CT)f2bf(v);
        else                           C[idx] = (CT)v;
      }
    }
  }
}

// ---------------- transpose + cast f32 -> bf16: dst[c][r] = src[r][c] -------
__global__ void transpose_cast_k(const float* __restrict__ src,
                                 unsigned short* __restrict__ dst,
                                 int R, int Ccols, long long sS, long long sD) {
  __shared__ float tile[32][33];
  src += (long long)blockIdx.z * sS;
  dst += (long long)blockIdx.z * sD;
  const int rb = blockIdx.y * 32, cb = blockIdx.x * 32;
  const int tx = threadIdx.x, ty = threadIdx.y;  // 32 x 8
#pragma unroll
  for (int k = 0; k < 4; ++k)
    tile[ty + k * 8][tx] = src[(long long)(rb + ty + k * 8) * Ccols + cb + tx];
  __syncthreads();
#pragma unroll
  for (int k = 0; k < 4; ++k)
    dst[(long long)(cb + ty + k * 8) * R + rb + tx] = f2bf(tile[tx][ty + k * 8]);
}

// ---------------- plain cast f32 -> bf16 ------------------------------------
__global__ void cast_f32_bf16_k(const float* __restrict__ src,
                                unsigned short* __restrict__ dst, long long n4) {
  long long i = (long long)blockIdx.x * 256 + threadIdx.x;
  const long long stride = (long long)gridDim.x * 256;
  for (; i < n4; i += stride) {
    float4 v = ((const float4*)src)[i];
    ushort4 o;
    o.x = f2bf(v.x); o.y = f2bf(v.y); o.z = f2bf(v.z); o.w = f2bf(v.w);
    ((ushort4*)dst)[i] = o;
  }
}

// ---------------- row softmax over 1024, f32 in, bf16 out -------------------
__global__ __launch_bounds__(256)
void softmax_k(const float* __restrict__ E, unsigned short* __restrict__ P) {
  __shared__ float sm[8];
  const long long row = blockIdx.x;
  const int t = threadIdx.x, w = t >> 6, lane = t & 63;
  float4 v = ((const float4*)E)[row * 256 + t];
  const float scale = 0.044194173824159216f;  // 1/sqrt(512)
  v.x *= scale; v.y *= scale; v.z *= scale; v.w *= scale;
  float mx = fmaxf(fmaxf(v.x, v.y), fmaxf(v.z, v.w));
#pragma unroll
  for (int m = 1; m < 64; m <<= 1) mx = fmaxf(mx, __shfl_xor(mx, m));
  if (lane == 0) sm[w] = mx;
  __syncthreads();
  mx = fmaxf(fmaxf(sm[0], sm[1]), fmaxf(sm[2], sm[3]));
  float e0 = __expf(v.x - mx), e1 = __expf(v.y - mx);
  float e2 = __expf(v.z - mx), e3 = __expf(v.w - mx);
  float s = e0 + e1 + e2 + e3;
#pragma unroll
  for (int m = 1; m < 64; m <<= 1) s += __shfl_xor(s, m);
  if (lane == 0) sm[4 + w] = s;
  __syncthreads();
  s = sm[4] + sm[5] + sm[6] + sm[7];
  const float inv = 1.0f / s;
  ushort4 o;
  o.x = f2bf(e0 * inv); o.y = f2bf(e1 * inv);
  o.z = f2bf(e2 * inv); o.w = f2bf(e3 * inv);
  ((ushort4*)P)[row * 256 + t] = o;
}

// ---------------- block reduce (sum pair) -----------------------------------
DEV void breduce2(float& a, float& b, float* sm, int w, int lane) {
#pragma unroll
  for (int m = 1; m < 64; m <<= 1) { a += __shfl_xor(a, m); b += __shfl_xor(b, m); }
  if (lane == 0) { sm[w] = a; sm[4 + w] = b; }
  __syncthreads();
  a = sm[0] + sm[1] + sm[2] + sm[3];
  b = sm[4] + sm[5] + sm[6] + sm[7];
  __syncthreads();
}

// ---- LN(concat(out2,q)) then LN(concat(attn_out,q)) -> xln bf16 [row,1536] -
__global__ __launch_bounds__(256)
void ln_concat_k(const float* __restrict__ out2, const float* __restrict__ query,
                 const float* __restrict__ ga, const float* __restrict__ ba,
                 const float* __restrict__ g1, const float* __restrict__ b1,
                 unsigned short* __restrict__ xln) {
  __shared__ float sm[8];
  const long long row = blockIdx.x;
  const int t = threadIdx.x, w = t >> 6, lane = t & 63;
  const float* o = out2 + row * 512;
  const float* q = query + row * 512;
  float c0 = o[t], c1 = o[t + 256], c2 = q[t], c3 = q[t + 256];
  float s = c0 + c1 + c2 + c3;
  float ss = c0 * c0 + c1 * c1 + c2 * c2 + c3 * c3;
  breduce2(s, ss, sm, w, lane);
  float mu = s * (1.0f / 1024.0f);
  float var = ss * (1.0f / 1024.0f) - mu * mu;
  float rs = rsqrtf(var + 1e-5f);
  float a0 = (c0 - mu) * rs * ga[t] + ba[t];
  float a1 = (c1 - mu) * rs * ga[t + 256] + ba[t + 256];
  float a2 = (c2 - mu) * rs * ga[t + 512] + ba[t + 512];
  float a3 = (c3 - mu) * rs * ga[t + 768] + ba[t + 768];
  float s2 = a0 + a1 + a2 + a3 + c2 + c3;
  float ss2 = a0*a0 + a1*a1 + a2*a2 + a3*a3 + c2*c2 + c3*c3;
  breduce2(s2, ss2, sm, w, lane);
  float mu2 = s2 * (1.0f / 1536.0f);
  float var2 = ss2 * (1.0f / 1536.0f) - mu2 * mu2;
  float rs2 = rsqrtf(var2 + 1e-5f);
  unsigned short* xr = xln + row * 1536;
  xr[t]        = f2bf((a0 - mu2) * rs2 * g1[t] + b1[t]);
  xr[t + 256]  = f2bf((a1 - mu2) * rs2 * g1[t + 256] + b1[t + 256]);
  xr[t + 512]  = f2bf((a2 - mu2) * rs2 * g1[t + 512] + b1[t + 512]);
  xr[t + 768]  = f2bf((a3 - mu2) * rs2 * g1[t + 768] + b1[t + 768]);
  xr[t + 1024] = f2bf((c2 - mu2) * rs2 * g1[t + 1024] + b1[t + 1024]);
  xr[t + 1280] = f2bf((c3 - mu2) * rs2 * g1[t + 1280] + b1[t + 1280]);
}

// ---------------- final LN over 1536, f32 -> f32 ----------------------------
__global__ __launch_bounds__(256)
void ln_final_k(const float* __restrict__ f, const float* __restrict__ g2,
                const float* __restrict__ b2, float* __restrict__ out) {
  __shared__ float sm[8];
  const long long row = blockIdx.x;
  const int t = threadIdx.x, w = t >> 6, lane = t & 63;
  const float* fr = f + row * 1536;
  float v[6];
  float s = 0.f, ss = 0.f;
#pragma unroll
  for (int j = 0; j < 6; ++j) { v[j] = fr[t + j * 256]; s += v[j]; ss += v[j] * v[j]; }
  breduce2(s, ss, sm, w, lane);
  float mu = s * (1.0f / 1536.0f);
  float var = ss * (1.0f / 1536.0f) - mu * mu;
  float rs = rsqrtf(var + 1e-5f);
  float* orow = out + row * 1536;
#pragma unroll
  for (int j = 0; j < 6; ++j)
    orow[t + j * 256] = (v[j] - mu) * rs * g2[t + j * 256] + b2[t + j * 256];
}

// ---------------------------------------------------------------------------
extern "C" void kernel_launch(void* const* d_in, const int* in_sizes, int n_in,
                              void* d_out, int out_size, void* d_ws, size_t ws_size,
                              hipStream_t stream) {
  const float* value = (const float*)d_in[0];
  const float* key   = (const float*)d_in[1];
  const float* query = (const float*)d_in[2];
  const float* Wk  = (const float*)d_in[3];
  const float* Wq  = (const float*)d_in[4];
  const float* Wo  = (const float*)d_in[5];
  const float* bo  = (const float*)d_in[6];
  const float* ga  = (const float*)d_in[7];
  const float* ba  = (const float*)d_in[8];
  const float* g1  = (const float*)d_in[9];
  const float* b1  = (const float*)d_in[10];
  const float* W1  = (const float*)d_in[11];
  const float* bf1 = (const float*)d_in[12];
  const float* W2  = (const float*)d_in[13];
  const float* bf2 = (const float*)d_in[14];
  const float* g2  = (const float*)d_in[15];
  const float* b2  = (const float*)d_in[16];
  float* out = (float*)d_out;
  char* ws = (char*)d_ws;

  // ---- workspace map (bytes), peak ~201 MB (lifetimes as in round 2) ------
  const size_t oW1T = 0;                   // [3072][1536] bf16
  const size_t oWkT = 9437184;
  const size_t oWqT = 9961472;
  const size_t oWoT = 10485760;
  const size_t oVT  = 11010048;            // [16][512][1024] bf16
  const size_t oKeyB = 27787264;           // [16384][512] bf16
  const size_t oQryB = 44564480;
  const size_t oKp   = 61341696;
  const size_t oQp   = 78118912;
  const size_t oE    = 100663296;          // [16][1024][1024] f32
  const size_t oP    = oKeyB;              // bf16 (reuse keyB+qryB)
  const size_t oO    = oKp;                // bf16 (reuse kp)
  const size_t oOut2 = oQp;                // f32 (reuse qp + E-head)
  const size_t oXln  = 27787264;           // bf16 (reuse P+O zones)
  const size_t oH    = 100663296;          // [16384][3072] bf16 (E zone +)
  const size_t oW2T  = 201326592;          // [1536][3072] bf16
  const size_t oF    = 0;                  // [16384][1536] f32 (low zone dead)

  unsigned short* W1T = (unsigned short*)(ws + oW1T);
  unsigned short* WkT = (unsigned short*)(ws + oWkT);
  unsigned short* WqT = (unsigned short*)(ws + oWqT);
  unsigned short* WoT = (unsigned short*)(ws + oWoT);
  unsigned short* W2T = (unsigned short*)(ws + oW2T);
  unsigned short* VT  = (unsigned short*)(ws + oVT);
  unsigned short* keyB = (unsigned short*)(ws + oKeyB);
  unsigned short* qryB = (unsigned short*)(ws + oQryB);
  unsigned short* kp  = (unsigned short*)(ws + oKp);
  unsigned short* qp  = (unsigned short*)(ws + oQp);
  float*          E   = (float*)(ws + oE);
  unsigned short* P   = (unsigned short*)(ws + oP);
  unsigned short* O   = (unsigned short*)(ws + oO);
  float*          out2 = (float*)(ws + oOut2);
  unsigned short* xln = (unsigned short*)(ws + oXln);
  unsigned short* h   = (unsigned short*)(ws + oH);
  float*          f   = (float*)(ws + oF);

  const dim3 tb(32, 8);
  transpose_cast_k<<<dim3(16, 16, 1), tb, 0, stream>>>(Wk, WkT, 512, 512, 0, 0);
  transpose_cast_k<<<dim3(16, 16, 1), tb, 0, stream>>>(Wq, WqT, 512, 512, 0, 0);
  transpose_cast_k<<<dim3(16, 16, 1), tb, 0, stream>>>(Wo, WoT, 512, 512, 0, 0);
  transpose_cast_k<<<dim3(96, 48, 1), tb, 0, stream>>>(W1, W1T, 1536, 3072, 0, 0);
  transpose_cast_k<<<dim3(48, 96, 1), tb, 0, stream>>>(W2, W2T, 3072, 1536, 0, 0);
  transpose_cast_k<<<dim3(16, 32, 16), tb, 0, stream>>>(value, VT, 1024, 512, 524288, 524288);
  cast_f32_bf16_k<<<2048, 256, 0, stream>>>(key,   keyB, 2097152);
  cast_f32_bf16_k<<<2048, 256, 0, stream>>>(query, qryB, 2097152);

  // G1/G2: projections [16384,512] = [16384,512]x[512,512]
  gemm256<unsigned short, false, false><<<128, 512, 0, stream>>>(
      keyB, WkT, kp, nullptr, 16384, 512, 512, 2, 64, 0, 0, 0);
  gemm256<unsigned short, false, false><<<128, 512, 0, stream>>>(
      qryB, WqT, qp, nullptr, 16384, 512, 512, 2, 64, 0, 0, 0);
  // G3: energy (x16): E[b] = qp[b] @ kp[b]^T   [1024,1024], K=512
  gemm256<float, false, false><<<256, 512, 0, stream>>>(
      qp, kp, E, nullptr, 1024, 1024, 512, 4, 4, 524288, 524288, 1048576);
  softmax_k<<<16384, 256, 0, stream>>>(E, P);
  // G4: O[b] = P[b] @ value[b]   [1024,512], K=1024
  gemm256<unsigned short, false, false><<<128, 512, 0, stream>>>(
      P, VT, O, nullptr, 1024, 512, 1024, 2, 4, 1048576, 524288, 524288);
  // G5: out2 = O @ Wo + bo
  gemm256<float, true, false><<<128, 512, 0, stream>>>(
      O, WoT, out2, bo, 16384, 512, 512, 2, 64, 0, 0, 0);
  ln_concat_k<<<16384, 256, 0, stream>>>(out2, query, ga, ba, g1, b1, xln);
  // G6: h = relu(xln @ W1 + bf1)   [16384,3072], K=1536
  gemm256<unsigned short, true, true><<<768, 512, 0, stream>>>(
      xln, W1T, h, bf1, 16384, 3072, 1536, 12, 64, 0, 0, 0);
  // G7: f = h @ W2 + bf2   [16384,1536], K=3072
  gemm256<float, true, false><<<384, 512, 0, stream>>>(
      h, W2T, f, bf2, 16384, 1536, 3072, 6, 64, 0, 0, 0);
  ln_final_k<<<16384, 256, 0, stream>>>(f, g2, b2, out);
}

// Round 10
// 758.927 us; speedup vs baseline: 1.1387x; 1.0162x over previous
//
#include <hip/hip_runtime.h>

// ---------------------------------------------------------------------------
// TransformerBlock on MI355X (gfx950).
// GEMM r10: 256x256 tile, BK=32, 4-slot LDS ring (128 KiB), 8 waves (2Mx4N),
// ONE barrier per K-tile, register double-buffered fragments (ds_read tile
// t+1 while MFMA on tile t -> MFMA cluster has no lgkm dependency),
// counted vmcnt(4) steady state (tiles t+2,t+3 in flight), LDS XOR swizzle
// via pre-swizzled global source (T2), XCD-bijective block swizzle (T1).
// r9 measured: 4-barrier version = MfmaUtil 33.8%, bank-conflict 0,
// all pipes idle -> barrier/latency-bound. This round removes 3 of 4
// barriers and takes lgkm off the MFMA critical path.
// ---------------------------------------------------------------------------

typedef __attribute__((ext_vector_type(8))) __bf16 bf16x8;
typedef __attribute__((ext_vector_type(4))) float f32x4;

#define DEV static __device__ __forceinline__

DEV unsigned short f2bf(float f) {
  union { float f; unsigned int u; } x; x.f = f;
  unsigned int u = x.u + 0x7fffu + ((x.u >> 16) & 1u);   // RNE
  return (unsigned short)(u >> 16);
}

DEV void gll16(const void* g, void* l) {
  __builtin_amdgcn_global_load_lds(
      (const __attribute__((address_space(1))) void*)g,
      (__attribute__((address_space(3))) void*)l, 16, 0, 0);
}

#define MFMA16(a, b, c) (c) = __builtin_amdgcn_mfma_f32_16x16x32_bf16((a), (b), (c), 0, 0, 0)

// One K-tile iteration. CUR regs hold tile T's fragments; reads tile T+1
// into NXT regs; stages tile T+3; 32 MFMAs on CUR; counted vmcnt; barrier.
// Residency invariant: end-of-iter-T wait guarantees tile T+2 in LDS.
#define GBODY(T, AVC, BVC, AVN, BVN)                                        \
  {                                                                         \
    const int tt = (T);                                                     \
    if (tt + 1 < NT) {                                                      \
      const unsigned short* sa_ = lds + ((tt + 1) & 3) * 16384;             \
      const unsigned short* sb_ = sa_ + 8192;                               \
      _Pragma("unroll")                                                     \
      for (int m_ = 0; m_ < 8; ++m_)                                        \
        AVN[m_] = *(const bf16x8*)(sa_ + aoff + m_ * 512);                  \
      _Pragma("unroll")                                                     \
      for (int n_ = 0; n_ < 4; ++n_)                                        \
        BVN[n_] = *(const bf16x8*)(sb_ + boff + n_ * 512);                  \
    }                                                                       \
    if (tt + 3 < NT) {                                                      \
      const int ss_ = (tt + 3) & 3;                                         \
      gll16(gA0 + (long long)(tt + 3) * 32, Lb + (ss_ << 15) + dA0);        \
      gll16(gA1 + (long long)(tt + 3) * 32, Lb + (ss_ << 15) + dA1);        \
      gll16(gB0 + (long long)(tt + 3) * 32, Lb + (ss_ << 15) + 16384 + dA0);\
      gll16(gB1 + (long long)(tt + 3) * 32, Lb + (ss_ << 15) + 16384 + dA1);\
    }                                                                       \
    _Pragma("unroll")                                                       \
    for (int m_ = 0; m_ < 8; ++m_) {                                        \
      MFMA16(AVC[m_], BVC[0], acc[m_][0]);                                  \
      MFMA16(AVC[m_], BVC[1], acc[m_][1]);                                  \
      MFMA16(AVC[m_], BVC[2], acc[m_][2]);                                  \
      MFMA16(AVC[m_], BVC[3], acc[m_][3]);                                  \
    }                                                                       \
    if (tt + 3 < NT)      asm volatile("s_waitcnt vmcnt(4)" ::: "memory");  \
    else if (tt + 2 < NT) asm volatile("s_waitcnt vmcnt(0)" ::: "memory");  \
    __builtin_amdgcn_sched_barrier(0);                                      \
    __builtin_amdgcn_s_barrier();                                           \
    __builtin_amdgcn_sched_barrier(0);                                      \
  }

// ---------------- GEMM: C[M,N] = A[M,K](bf16) * Bt[N,K](bf16)^T -------------
// 256x256 tile, BK=32, 512 thr = 8 waves (2Mx4N); per wave 128x64 out =
// acc[8][4] f32x4. LDS ring: 4 slots x (A 16KB + B 16KB). Tile t in slot t&3;
// iter t stages tile t+3 into slot (t-1)&3 (its readers retired before the
// end-of-(t-1) barrier via the lgkm waits feeding iter-(t-1)'s MFMAs).
// vmcnt(4) at end of iter t => tile t+2 resident (only t+3's 4 loads may
// remain in flight); tail: vmcnt(0) at t=NT-2, none after.
// LDS swizzle: 16B-granule g at row r stored at g^((r>>1)&3), realized by
// swizzled GLOBAL source column + matching XOR on the ds_read address.
template <typename CT, bool BIAS, bool RELU>
__global__ __launch_bounds__(512, 2)
void gemm256(const unsigned short* __restrict__ A,
             const unsigned short* __restrict__ Bt,
             CT* __restrict__ C, const float* __restrict__ bias,
             int M, int N, int K, int nbx, int nby,
             long long sA, long long sB, long long sC) {
  __shared__ __align__(16) unsigned short lds[65536];   // 128 KiB

  // T1: XCD-bijective swizzle (gridDim.x % 8 == 0 at every call site)
  const int cpx = gridDim.x >> 3;
  const int id = blockIdx.x;
  const int swz = (id & 7) * cpx + (id >> 3);
  const int nxy = nbx * nby;
  const int bz = swz / nxy;
  const int rxy = swz - bz * nxy;
  const int by = rxy / nbx;
  const int bx = rxy - by * nbx;

  A  += (long long)bz * sA;
  Bt += (long long)bz * sB;
  C  += (long long)bz * sC;
  const int rowBase = by * 256, colBase = bx * 256;

  const int tid = threadIdx.x;
  const int w = tid >> 6, lane = tid & 63;
  const int wm = w >> 2, wn = w & 3;

  // staging: wave w stages chunks w and w+8 of each 16KB unit.
  // chunk c = rows c*16..c*16+15 (64 B/row); lane l -> row c*16 + (l>>2),
  // 16B slot l&3; source k-granule = (l&3) ^ ((l>>3)&3)
  const int lr = lane >> 2;
  const int sc = (((lane & 3) ^ ((lane >> 3) & 3)) << 3);   // element offset
  const long long Kll = K;
  const unsigned short* gA0 = A  + (long long)(rowBase + w * 16 + lr) * Kll + sc;
  const unsigned short* gA1 = gA0 + 128 * Kll;              // chunk w+8
  const unsigned short* gB0 = Bt + (long long)(colBase + w * 16 + lr) * Kll + sc;
  const unsigned short* gB1 = gB0 + 128 * Kll;
  char* const Lb = (char*)lds;
  const int dA0 = w * 1024, dA1 = (w + 8) * 1024;           // chunk byte offsets

  // compute-read: row = base + (lane&15); k-granule g = lane>>4 stored at
  // slot g ^ ((row>>1)&3) = g ^ ((lane>>1)&3)   (bases are %16==0)
  const int sig = (lane >> 4) ^ ((lane >> 1) & 3);
  const int aoff = (wm * 128 + (lane & 15)) * 32 + sig * 8;  // ushort offset
  const int boff = (wn * 64 + (lane & 15)) * 32 + sig * 8;

  f32x4 acc[8][4];
#pragma unroll
  for (int m = 0; m < 8; ++m)
#pragma unroll
    for (int n = 0; n < 4; ++n) acc[m][n] = f32x4{0.f, 0.f, 0.f, 0.f};

  const int NT = K >> 5;   // always even and >= 16 at our call sites

  // prologue: stage tiles 0..2; wait tiles 0,1; read tile-0 fragments
  for (int p = 0; p < 3; ++p) {
    gll16(gA0 + (long long)p * 32, Lb + (p << 15) + dA0);
    gll16(gA1 + (long long)p * 32, Lb + (p << 15) + dA1);
    gll16(gB0 + (long long)p * 32, Lb + (p << 15) + 16384 + dA0);
    gll16(gB1 + (long long)p * 32, Lb + (p << 15) + 16384 + dA1);
  }
  asm volatile("s_waitcnt vmcnt(4)" ::: "memory");   // tiles 0,1 resident
  __builtin_amdgcn_sched_barrier(0);
  __builtin_amdgcn_s_barrier();
  __builtin_amdgcn_sched_barrier(0);

  bf16x8 avA[8], bvA[4], avB[8], bvB[4];
#pragma unroll
  for (int m = 0; m < 8; ++m) avA[m] = *(const bf16x8*)(lds + aoff + m * 512);
#pragma unroll
  for (int n = 0; n < 4; ++n) bvA[n] = *(const bf16x8*)(lds + 8192 + boff + n * 512);

  for (int t = 0; t < NT; t += 2) {
    GBODY(t,     avA, bvA, avB, bvB);
    GBODY(t + 1, avB, bvB, avA, bvA);
  }

  // -------- epilogue: C/D col = lane&15, row = (lane>>4)*4 + r --------
  const int r0 = rowBase + wm * 128 + ((lane >> 4) << 2);
  const int cb = colBase + wn * 64 + (lane & 15);
#pragma unroll
  for (int n = 0; n < 4; ++n) {
    const int col = cb + n * 16;
    float bvv = 0.f;
    if constexpr (BIAS) bvv = bias[col];
#pragma unroll
    for (int m = 0; m < 8; ++m) {
#pragma unroll
      for (int r = 0; r < 4; ++r) {
        float v = acc[m][n][r] + bvv;
        if constexpr (RELU) v = v > 0.f ? v : 0.f;
        const long long idx = (long long)(r0 + m * 16 + r) * N + col;
        if constexpr (sizeof(CT) == 2) C[idx] = (CT)f2bf(v);
        else                           C[idx] = (CT)v;
      }
    }
  }
}

// ---------------- transpose + cast f32 -> bf16: dst[c][r] = src[r][c] -------
__global__ void transpose_cast_k(const float* __restrict__ src,
                                 unsigned short* __restrict__ dst,
                                 int R, int Ccols, long long sS, long long sD) {
  __shared__ float tile[32][33];
  src += (long long)blockIdx.z * sS;
  dst += (long long)blockIdx.z * sD;
  const int rb = blockIdx.y * 32, cb = blockIdx.x * 32;
  const int tx = threadIdx.x, ty = threadIdx.y;  // 32 x 8
#pragma unroll
  for (int k = 0; k < 4; ++k)
    tile[ty + k * 8][tx] = src[(long long)(rb + ty + k * 8) * Ccols + cb + tx];
  __syncthreads();
#pragma unroll
  for (int k = 0; k < 4; ++k)
    dst[(long long)(cb + ty + k * 8) * R + rb + tx] = f2bf(tile[tx][ty + k * 8]);
}

// ---------------- plain cast f32 -> bf16 ------------------------------------
__global__ void cast_f32_bf16_k(const float* __restrict__ src,
                                unsigned short* __restrict__ dst, long long n4) {
  long long i = (long long)blockIdx.x * 256 + threadIdx.x;
  const long long stride = (long long)gridDim.x * 256;
  for (; i < n4; i += stride) {
    float4 v = ((const float4*)src)[i];
    ushort4 o;
    o.x = f2bf(v.x); o.y = f2bf(v.y); o.z = f2bf(v.z); o.w = f2bf(v.w);
    ((ushort4*)dst)[i] = o;
  }
}

// ---------------- row softmax over 1024, f32 in, bf16 out -------------------
__global__ __launch_bounds__(256)
void softmax_k(const float* __restrict__ E, unsigned short* __restrict__ P) {
  __shared__ float sm[8];
  const long long row = blockIdx.x;
  const int t = threadIdx.x, w = t >> 6, lane = t & 63;
  float4 v = ((const float4*)E)[row * 256 + t];
  const float scale = 0.044194173824159216f;  // 1/sqrt(512)
  v.x *= scale; v.y *= scale; v.z *= scale; v.w *= scale;
  float mx = fmaxf(fmaxf(v.x, v.y), fmaxf(v.z, v.w));
#pragma unroll
  for (int m = 1; m < 64; m <<= 1) mx = fmaxf(mx, __shfl_xor(mx, m));
  if (lane == 0) sm[w] = mx;
  __syncthreads();
  mx = fmaxf(fmaxf(sm[0], sm[1]), fmaxf(sm[2], sm[3]));
  float e0 = __expf(v.x - mx), e1 = __expf(v.y - mx);
  float e2 = __expf(v.z - mx), e3 = __expf(v.w - mx);
  float s = e0 + e1 + e2 + e3;
#pragma unroll
  for (int m = 1; m < 64; m <<= 1) s += __shfl_xor(s, m);
  if (lane == 0) sm[4 + w] = s;
  __syncthreads();
  s = sm[4] + sm[5] + sm[6] + sm[7];
  const float inv = 1.0f / s;
  ushort4 o;
  o.x = f2bf(e0 * inv); o.y = f2bf(e1 * inv);
  o.z = f2bf(e2 * inv); o.w = f2bf(e3 * inv);
  ((ushort4*)P)[row * 256 + t] = o;
}

// ---------------- block reduce (sum pair) -----------------------------------
DEV void breduce2(float& a, float& b, float* sm, int w, int lane) {
#pragma unroll
  for (int m = 1; m < 64; m <<= 1) { a += __shfl_xor(a, m); b += __shfl_xor(b, m); }
  if (lane == 0) { sm[w] = a; sm[4 + w] = b; }
  __syncthreads();
  a = sm[0] + sm[1] + sm[2] + sm[3];
  b = sm[4] + sm[5] + sm[6] + sm[7];
  __syncthreads();
}

// ---- LN(concat(out2,q)) then LN(concat(attn_out,q)) -> xln bf16 [row,1536] -
__global__ __launch_bounds__(256)
void ln_concat_k(const float* __restrict__ out2, const float* __restrict__ query,
                 const float* __restrict__ ga, const float* __restrict__ ba,
                 const float* __restrict__ g1, const float* __restrict__ b1,
                 unsigned short* __restrict__ xln) {
  __shared__ float sm[8];
  const long long row = blockIdx.x;
  const int t = threadIdx.x, w = t >> 6, lane = t & 63;
  const float* o = out2 + row * 512;
  const float* q = query + row * 512;
  float c0 = o[t], c1 = o[t + 256], c2 = q[t], c3 = q[t + 256];
  float s = c0 + c1 + c2 + c3;
  float ss = c0 * c0 + c1 * c1 + c2 * c2 + c3 * c3;
  breduce2(s, ss, sm, w, lane);
  float mu = s * (1.0f / 1024.0f);
  float var = ss * (1.0f / 1024.0f) - mu * mu;
  float rs = rsqrtf(var + 1e-5f);
  float a0 = (c0 - mu) * rs * ga[t] + ba[t];
  float a1 = (c1 - mu) * rs * ga[t + 256] + ba[t + 256];
  float a2 = (c2 - mu) * rs * ga[t + 512] + ba[t + 512];
  float a3 = (c3 - mu) * rs * ga[t + 768] + ba[t + 768];
  float s2 = a0 + a1 + a2 + a3 + c2 + c3;
  float ss2 = a0*a0 + a1*a1 + a2*a2 + a3*a3 + c2*c2 + c3*c3;
  breduce2(s2, ss2, sm, w, lane);
  float mu2 = s2 * (1.0f / 1536.0f);
  float var2 = ss2 * (1.0f / 1536.0f) - mu2 * mu2;
  float rs2 = rsqrtf(var2 + 1e-5f);
  unsigned short* xr = xln + row * 1536;
  xr[t]        = f2bf((a0 - mu2) * rs2 * g1[t] + b1[t]);
  xr[t + 256]  = f2bf((a1 - mu2) * rs2 * g1[t + 256] + b1[t + 256]);
  xr[t + 512]  = f2bf((a2 - mu2) * rs2 * g1[t + 512] + b1[t + 512]);
  xr[t + 768]  = f2bf((a3 - mu2) * rs2 * g1[t + 768] + b1[t + 768]);
  xr[t + 1024] = f2bf((c2 - mu2) * rs2 * g1[t + 1024] + b1[t + 1024]);
  xr[t + 1280] = f2bf((c3 - mu2) * rs2 * g1[t + 1280] + b1[t + 1280]);
}

// ---------------- final LN over 1536, f32 -> f32 ----------------------------
__global__ __launch_bounds__(256)
void ln_final_k(const float* __restrict__ f, const float* __restrict__ g2,
                const float* __restrict__ b2, float* __restrict__ out) {
  __shared__ float sm[8];
  const long long row = blockIdx.x;
  const int t = threadIdx.x, w = t >> 6, lane = t & 63;
  const float* fr = f + row * 1536;
  float v[6];
  float s = 0.f, ss = 0.f;
#pragma unroll
  for (int j = 0; j < 6; ++j) { v[j] = fr[t + j * 256]; s += v[j]; ss += v[j] * v[j]; }
  breduce2(s, ss, sm, w, lane);
  float mu = s * (1.0f / 1536.0f);
  float var = ss * (1.0f / 1536.0f) - mu * mu;
  float rs = rsqrtf(var + 1e-5f);
  float* orow = out + row * 1536;
#pragma unroll
  for (int j = 0; j < 6; ++j)
    orow[t + j * 256] = (v[j] - mu) * rs * g2[t + j * 256] + b2[t + j * 256];
}

// ---------------------------------------------------------------------------
extern "C" void kernel_launch(void* const* d_in, const int* in_sizes, int n_in,
                              void* d_out, int out_size, void* d_ws, size_t ws_size,
                              hipStream_t stream) {
  const float* value = (const float*)d_in[0];
  const float* key   = (const float*)d_in[1];
  const float* query = (const float*)d_in[2];
  const float* Wk  = (const float*)d_in[3];
  const float* Wq  = (const float*)d_in[4];
  const float* Wo  = (const float*)d_in[5];
  const float* bo  = (const float*)d_in[6];
  const float* ga  = (const float*)d_in[7];
  const float* ba  = (const float*)d_in[8];
  const float* g1  = (const float*)d_in[9];
  const float* b1  = (const float*)d_in[10];
  const float* W1  = (const float*)d_in[11];
  const float* bf1 = (const float*)d_in[12];
  const float* W2  = (const float*)d_in[13];
  const float* bf2 = (const float*)d_in[14];
  const float* g2  = (const float*)d_in[15];
  const float* b2  = (const float*)d_in[16];
  float* out = (float*)d_out;
  char* ws = (char*)d_ws;

  // ---- workspace map (bytes), peak ~201 MB (lifetimes as in round 2) ------
  const size_t oW1T = 0;                   // [3072][1536] bf16
  const size_t oWkT = 9437184;
  const size_t oWqT = 9961472;             // = oWkT + 524288 (G1/G2 batch stride)
  const size_t oWoT = 10485760;
  const size_t oVT  = 11010048;            // [16][512][1024] bf16
  const size_t oKeyB = 27787264;           // [16384][512] bf16
  const size_t oQryB = 44564480;           // = oKeyB + 16 MB (batch stride)
  const size_t oKp   = 61341696;
  const size_t oQp   = 78118912;           // = oKp + 16 MB (batch stride)
  const size_t oE    = 100663296;          // [16][1024][1024] f32
  const size_t oP    = oKeyB;              // bf16 (reuse keyB+qryB)
  const size_t oO    = oKp;                // bf16 (reuse kp)
  const size_t oOut2 = oQp;                // f32 (reuse qp + E-head)
  const size_t oXln  = 27787264;           // bf16 (reuse P+O zones)
  const size_t oH    = 100663296;          // [16384][3072] bf16 (E zone +)
  const size_t oW2T  = 201326592;          // [1536][3072] bf16
  const size_t oF    = 0;                  // [16384][1536] f32 (low zone dead)

  unsigned short* W1T = (unsigned short*)(ws + oW1T);
  unsigned short* WkT = (unsigned short*)(ws + oWkT);
  unsigned short* WqT = (unsigned short*)(ws + oWqT);
  unsigned short* WoT = (unsigned short*)(ws + oWoT);
  unsigned short* W2T = (unsigned short*)(ws + oW2T);
  unsigned short* VT  = (unsigned short*)(ws + oVT);
  unsigned short* keyB = (unsigned short*)(ws + oKeyB);
  unsigned short* qryB = (unsigned short*)(ws + oQryB);
  unsigned short* kp  = (unsigned short*)(ws + oKp);
  unsigned short* qp  = (unsigned short*)(ws + oQp);
  float*          E   = (float*)(ws + oE);
  unsigned short* P   = (unsigned short*)(ws + oP);
  unsigned short* O   = (unsigned short*)(ws + oO);
  float*          out2 = (float*)(ws + oOut2);
  unsigned short* xln = (unsigned short*)(ws + oXln);
  unsigned short* h   = (unsigned short*)(ws + oH);
  float*          f   = (float*)(ws + oF);

  const dim3 tb(32, 8);
  transpose_cast_k<<<dim3(16, 16, 1), tb, 0, stream>>>(Wk, WkT, 512, 512, 0, 0);
  transpose_cast_k<<<dim3(16, 16, 1), tb, 0, stream>>>(Wq, WqT, 512, 512, 0, 0);
  transpose_cast_k<<<dim3(16, 16, 1), tb, 0, stream>>>(Wo, WoT, 512, 512, 0, 0);
  transpose_cast_k<<<dim3(96, 48, 1), tb, 0, stream>>>(W1, W1T, 1536, 3072, 0, 0);
  transpose_cast_k<<<dim3(48, 96, 1), tb, 0, stream>>>(W2, W2T, 3072, 1536, 0, 0);
  transpose_cast_k<<<dim3(16, 32, 16), tb, 0, stream>>>(value, VT, 1024, 512, 524288, 524288);
  cast_f32_bf16_k<<<2048, 256, 0, stream>>>(key,   keyB, 2097152);
  cast_f32_bf16_k<<<2048, 256, 0, stream>>>(query, qryB, 2097152);

  // G1+G2 merged (batched over bz=2): {kp,qp} = {keyB,qryB} @ {WkT,WqT}
  gemm256<unsigned short, false, false><<<256, 512, 0, stream>>>(
      keyB, WkT, kp, nullptr, 16384, 512, 512, 2, 64, 8388608, 262144, 8388608);
  // G3: energy (x16): E[b] = qp[b] @ kp[b]^T   [1024,1024], K=512
  gemm256<float, false, false><<<256, 512, 0, stream>>>(
      qp, kp, E, nullptr, 1024, 1024, 512, 4, 4, 524288, 524288, 1048576);
  softmax_k<<<16384, 256, 0, stream>>>(E, P);
  // G4: O[b] = P[b] @ value[b]   [1024,512], K=1024
  gemm256<unsigned short, false, false><<<128, 512, 0, stream>>>(
      P, VT, O, nullptr, 1024, 512, 1024, 2, 4, 1048576, 524288, 524288);
  // G5: out2 = O @ Wo + bo
  gemm256<float, true, false><<<128, 512, 0, stream>>>(
      O, WoT, out2, bo, 16384, 512, 512, 2, 64, 0, 0, 0);
  ln_concat_k<<<16384, 256, 0, stream>>>(out2, query, ga, ba, g1, b1, xln);
  // G6: h = relu(xln @ W1 + bf1)   [16384,3072], K=1536
  gemm256<unsigned short, true, true><<<768, 512, 0, stream>>>(
      xln, W1T, h, bf1, 16384, 3072, 1536, 12, 64, 0, 0, 0);
  // G7: f = h @ W2 + bf2   [16384,1536], K=3072
  gemm256<float, true, false><<<384, 512, 0, stream>>>(
      h, W2T, f, bf2, 16384, 1536, 3072, 6, 64, 0, 0, 0);
  ln_final_k<<<16384, 256, 0, stream>>>(f, g2, b2, out);
}